// Round 9
// baseline (157.135 us; speedup 1.0000x reference)
//
#include <hip/hip_runtime.h>
#include <hip/hip_fp16.h>
#include <math.h>

#define D_FEAT 100
#define ROW_STRIDE 300     // 3 * D_FEAT concatenated output blocks
#define ROWB 128u          // int8 table row = ONE 128-B cache line:
                           //   bytes 0..99   : biased-uint8 feats (b=rint(127x)+128)
                           //   bytes 100..111: pad 0x80 (decodes to 0)
                           //   bytes 112..115: f32 edge weight w = exp(-score)
                           //   bytes 116..127: pad 0x80
                           // row N = sentinel: w=0, feats decode to 0.
// dequant fold: x_avg = (Sum w*b)/(127*dsum) - 128/127

// ---------------------------------------------------------------------------
__device__ __forceinline__ float fast_tanh(float x) {
    float ax = fabsf(x);
    float e  = __expf(2.f * ax);
    float t  = 1.f - 2.f / (e + 1.f);
    return copysignf(t, x);
}

// biased-uint8 quantization of x in (-1,1): b = rint(127x) + 128 in [1,255]
__device__ __forceinline__ unsigned pb4(float x0, float x1, float x2, float x3) {
    unsigned b0 = (unsigned)(int)rintf(fmaf(x0, 127.f, 128.f));
    unsigned b1 = (unsigned)(int)rintf(fmaf(x1, 127.f, 128.f));
    unsigned b2 = (unsigned)(int)rintf(fmaf(x2, 127.f, 128.f));
    unsigned b3 = (unsigned)(int)rintf(fmaf(x3, 127.f, 128.f));
    return b0 | (b1 << 8) | (b2 << 16) | (b3 << 24);
}

__device__ __forceinline__ float half_reduce(float v) {
    #pragma unroll
    for (int off = 16; off; off >>= 1) v += __shfl_xor(v, off, 64);
    return v;
}

// ---------------------------------------------------------------------------
// Kernel 1: 2 nodes per wave + STREAMING CSR build + cols extraction.
//  CSR: adj rows are sorted; thread t owns edges 2t,2t+1 (one uint4 load),
//  writes start[j] at row boundaries -- no binary search, no dependent
//  random-load chains (the old 20-deep search dominated this kernel).
// Lane convention (shifted): lanes 1..25 hold elems 4(l-1)..4(l-1)+3.
// ---------------------------------------------------------------------------
__global__ __launch_bounds__(256) void tanh_score_kernel(
    const float* __restrict__ features,
    float* __restrict__ out,
    unsigned char* __restrict__ tab0,        // (N+1) x 128-B rows or null
    float* __restrict__ escore0,
    const float* __restrict__ none_rel,
    const int* __restrict__ adj,
    int* __restrict__ startArr,
    int* __restrict__ cols,                  // packed col indices (E)
    int E, int N)
{
    int gtid = blockIdx.x * blockDim.x + threadIdx.x;
    // cols extraction + streaming CSR boundaries (E even; grid covers E/2)
    if (gtid < (E >> 1)) {
        uint4 v = ((const uint4*)adj)[gtid];       // edges 2t,2t+1: {r0,c0,r1,c1}
        if (cols) ((int2*)cols)[gtid] = make_int2((int)v.y, (int)v.w);
        const int e  = gtid << 1;
        const int ra = (int)v.x, rb = (int)v.z;
        if (gtid == 0)
            for (int j = 0; j <= ra; ++j) startArr[j] = 0;
        for (int j = ra + 1; j <= rb; ++j) startArr[j] = e + 1;
        const int rc = (e + 2 < E) ? adj[2 * (e + 2)] : N;
        for (int j = rb + 1; j <= rc; ++j) startArr[j] = e + 2;
    }
    // sentinel row N: feats decode to 0, w = 0.0f (bytes 112..115)
    if (tab0 && gtid < 8) {
        uint4 z = make_uint4(0x80808080u, 0x80808080u, 0x80808080u, 0x80808080u);
        if (gtid == 7) z.x = 0u;                   // f32 0.0 at 112..115
        *(uint4*)(tab0 + (((size_t)N) << 7) + ((size_t)gtid << 4)) = z;
    }

    int waveId = gtid >> 6;
    int lane = threadIdx.x & 63;
    int h32  = lane >> 5;
    int l    = lane & 31;
    int n    = waveId * 2 + h32;
    const bool valid_n = (n < N);
    const bool fact = valid_n && (l >= 1) && (l <= 25);

    float x0 = 0.f, x1 = 0.f, x2 = 0.f, x3 = 0.f;
    if (fact) {
        float4 f = ((const float4*)(features + (size_t)n * D_FEAT))[l - 1];
        x0 = fast_tanh(f.x); x1 = fast_tanh(f.y);
        x2 = fast_tanh(f.z); x3 = fast_tanh(f.w);
        ((float4*)(out + (size_t)n * ROW_STRIDE))[l - 1] = make_float4(x0, x1, x2, x3);
    }
    unsigned char* row = tab0 ? (tab0 + ((size_t)n << 7)) : nullptr;
    if (row && valid_n) {
        if (l >= 1 && l <= 25) {
            *(unsigned*)(row + 4 * (l - 1)) = pb4(x0, x1, x2, x3);  // bytes 0..99
        } else if (l >= 26 && l != 29) {
            *(unsigned*)(row + 4 * (l - 1)) = 0x80808080u;          // 100..123 minus 112..115
        } else if (l == 0) {
            *(unsigned*)(row + 124) = 0x80808080u;                  // 124..127
        }
    }

    float nx = 0.f, ny = 0.f, nz = 0.f, nw = 0.f;
    if (l >= 1 && l <= 25) {
        float4 v = ((const float4*)none_rel)[l - 1];
        nx = v.x; ny = v.y; nz = v.z; nw = v.w;
    }
    float ss = half_reduce(nx * nx + ny * ny + nz * nz + nw * nw);
    float inv_nr = 1.f / fmaxf(sqrtf(ss), 1e-12f);

    float dot = half_reduce(x0 * nx + x1 * ny + x2 * nz + x3 * nw) * inv_nr;
    float sq  = half_reduce(x0 * x0 + x1 * x1 + x2 * x2 + x3 * x3);
    if (l == 0 && valid_n) {
        float es = __expf(-dot / fmaxf(sqrtf(sq), 1e-12f));
        escore0[n] = es;
        if (row) *(float*)(row + 112) = es;    // embedded weight
    }
}

// ---------------------------------------------------------------------------
// Kernel 2: fused attention, 2 nodes per wave, 128-B rows with embedded w.
//  Per 32-half: grp = hl>>3 picks the edge (4 per load), chunk = hl&7 the
//  16-B sub-block. Weight comes from the gathered row (lane grp*8+7, bytes
//  112..115) -> no esc gather. Invalid slots point at sentinel row N (w=0).
//  LOAD/ACC are split so that up to 8 line-gathers are in flight before any
//  consumption (deeper MLP for deg>16 nodes -- outstanding-miss-bound regime).
//  Lane hl owns features f0..f0+3, f0 = 16*chunk + 4*grp (bijection to
//  {0,4,...,124}); all row stores use offset f0 to match the read layout.
// ---------------------------------------------------------------------------
template <bool WRITE_TAB>
__global__ __launch_bounds__(256) void attn8_kernel(
    const unsigned char* __restrict__ tab,   // (N+1) x 128-B rows
    float* __restrict__ outp,
    unsigned char* __restrict__ tab_out,     // next table (WRITE_TAB)
    const int* __restrict__ cols,
    const int* __restrict__ start,
    const float* __restrict__ none_rel,
    int N)
{
    if constexpr (WRITE_TAB) {               // maintain sentinel in next table
        if (blockIdx.x == 0 && threadIdx.x < 8) {
            uint4 z = make_uint4(0x80808080u, 0x80808080u, 0x80808080u, 0x80808080u);
            if (threadIdx.x == 7) z.x = 0u;
            *(uint4*)(tab_out + (((size_t)N) << 7) + ((size_t)threadIdx.x << 4)) = z;
        }
    }

    const int waveId = (int)((blockIdx.x * blockDim.x + threadIdx.x) >> 6);
    const int lane = threadIdx.x & 63;
    const int h32  = lane >> 5;
    const int hl   = lane & 31;
    const int base = h32 << 5;
    const int n    = waveId * 2 + h32;
    const bool valid_n = (n < N);

    const int grp   = hl >> 3;                 // edge slot within a load
    const int chunk = hl & 7;                  // 16-B sub-block within row
    const unsigned suboff = (unsigned)(chunk << 4);
    const int wl = base + (grp << 3) + 7;      // lane holding w of my edge

    int e0 = 0, e1 = 0;
    if (valid_n) { e0 = start[n]; e1 = start[n + 1]; }
    const int deg = e1 - e0;
    int maxdeg = deg;
    { int o = __shfl_xor(maxdeg, 32, 64); maxdeg = maxdeg > o ? maxdeg : o; }

    // stage cols for up to 64 edges; invalid slots -> sentinel row N
    int c0 = N, c1 = N;
    if (hl < deg)      c0 = cols[e0 + hl];
    if (hl + 32 < deg) c1 = cols[e0 + hl + 32];

    float a[16];
    #pragma unroll
    for (int k = 0; k < 16; ++k) a[k] = 0.f;
    float dsum = 0.f;

#define ACC16(V, W)                                                           \
    {                                                                         \
        unsigned _d;                                                          \
        _d = (V).x;                                                           \
        a[0]  = fmaf((float)(_d & 255u),         (W), a[0]);                  \
        a[1]  = fmaf((float)((_d >> 8) & 255u),  (W), a[1]);                  \
        a[2]  = fmaf((float)((_d >> 16) & 255u), (W), a[2]);                  \
        a[3]  = fmaf((float)(_d >> 24),          (W), a[3]);                  \
        _d = (V).y;                                                           \
        a[4]  = fmaf((float)(_d & 255u),         (W), a[4]);                  \
        a[5]  = fmaf((float)((_d >> 8) & 255u),  (W), a[5]);                  \
        a[6]  = fmaf((float)((_d >> 16) & 255u), (W), a[6]);                  \
        a[7]  = fmaf((float)(_d >> 24),          (W), a[7]);                  \
        _d = (V).z;                                                           \
        a[8]  = fmaf((float)(_d & 255u),         (W), a[8]);                  \
        a[9]  = fmaf((float)((_d >> 8) & 255u),  (W), a[9]);                  \
        a[10] = fmaf((float)((_d >> 16) & 255u), (W), a[10]);                 \
        a[11] = fmaf((float)(_d >> 24),          (W), a[11]);                 \
        _d = (V).w;                                                           \
        a[12] = fmaf((float)(_d & 255u),         (W), a[12]);                 \
        a[13] = fmaf((float)((_d >> 8) & 255u),  (W), a[13]);                 \
        a[14] = fmaf((float)((_d >> 16) & 255u), (W), a[14]);                 \
        a[15] = fmaf((float)(_d >> 24),          (W), a[15]);                 \
    }

    // 4 line-gathers (16 edges per half) issued, not yet consumed
#define B16_LOAD(CST, RBASE, VA, VB, VC, VD)                                  \
    uint4 VA, VB, VC, VD;                                                     \
    {                                                                         \
        const int sA = base + (RBASE) + grp;                                  \
        const int cA_ = __shfl((CST), sA,      64);                           \
        const int cB_ = __shfl((CST), sA + 4,  64);                           \
        const int cC_ = __shfl((CST), sA + 8,  64);                           \
        const int cD_ = __shfl((CST), sA + 12, 64);                           \
        VA = *(const uint4*)(tab + (((size_t)(unsigned)cA_) << 7) + suboff);  \
        VB = *(const uint4*)(tab + (((size_t)(unsigned)cB_) << 7) + suboff);  \
        VC = *(const uint4*)(tab + (((size_t)(unsigned)cC_) << 7) + suboff);  \
        VD = *(const uint4*)(tab + (((size_t)(unsigned)cD_) << 7) + suboff);  \
    }

    // consume: w from the gathered rows (lane wl), dsum in-loop
#define B16_ACC(VA, VB, VC, VD)                                               \
    {                                                                         \
        const float wA = __shfl(__uint_as_float((VA).x), wl, 64);             \
        const float wB = __shfl(__uint_as_float((VB).x), wl, 64);             \
        const float wC = __shfl(__uint_as_float((VC).x), wl, 64);             \
        const float wD = __shfl(__uint_as_float((VD).x), wl, 64);             \
        dsum += wA + wB + wC + wD;                                            \
        ACC16(VA, wA) ACC16(VB, wB) ACC16(VC, wC) ACC16(VD, wD)               \
    }

    if (maxdeg > 0) {
        B16_LOAD(c0, 0, va0, va1, va2, va3)
        if (maxdeg > 16) {
            B16_LOAD(c0, 16, vb0, vb1, vb2, vb3)    // 8 gathers in flight
            B16_ACC(va0, va1, va2, va3)
            B16_ACC(vb0, vb1, vb2, vb3)
        } else {
            B16_ACC(va0, va1, va2, va3)
        }
    }
    if (maxdeg > 32) {
        B16_LOAD(c1, 0, vc0, vc1, vc2, vc3)
        if (maxdeg > 48) {
            B16_LOAD(c1, 16, vd0, vd1, vd2, vd3)
            B16_ACC(vc0, vc1, vc2, vc3)
            B16_ACC(vd0, vd1, vd2, vd3)
        } else {
            B16_ACC(vc0, vc1, vc2, vc3)
        }
    }
#undef B16_LOAD
#undef B16_ACC

    // deg > 64 tail (~never): one edge per pass, group 0 accumulates
    for (int e = e0 + 64; e < e1; ++e) {
        int c = cols[e];
        const uint4 v = *(const uint4*)(tab + (((size_t)(unsigned)c) << 7) + suboff);
        float wv = __shfl(__uint_as_float(v.x), base + 7, 64);
        if (grp == 0) { ACC16(v, wv) dsum += wv; }
    }
#undef ACC16

    // ---- combine the 4 edge-groups (same chunk, different grp) ----
    #pragma unroll
    for (int k = 0; k < 16; ++k) a[k] += __shfl_xor(a[k], 16, 64);
    #pragma unroll
    for (int k = 0; k < 16; ++k) a[k] += __shfl_xor(a[k], 8, 64);
    dsum += __shfl_xor(dsum, 16, 64);
    dsum += __shfl_xor(dsum, 8, 64);

    // ---- each lane finalizes its own 4 features: f0 = 16*chunk + 4*grp ----
    const float invd = (deg > 0) ? 1.f / (127.f * dsum) : 0.f;
    const float bsh  = (deg > 0) ? (-128.f / 127.f) : 0.f;
    const int f0 = (chunk << 4) + (grp << 2);
    const bool live = valid_n && (f0 < 100);   // f0 multiple of 4 -> f0+3 <= 99
    float r0 = 0.f, r1 = 0.f, r2 = 0.f, r3 = 0.f;
    if (live) {
        r0 = fast_tanh(fmaf(a[(grp << 2) + 0], invd, bsh));
        r1 = fast_tanh(fmaf(a[(grp << 2) + 1], invd, bsh));
        r2 = fast_tanh(fmaf(a[(grp << 2) + 2], invd, bsh));
        r3 = fast_tanh(fmaf(a[(grp << 2) + 3], invd, bsh));
    }

    // ---- next-layer score (WRITE_TAB): distinct features per lane, no dup
    float es = 0.f;
    if constexpr (WRITE_TAB) {
        float n0 = 0.f, n1 = 0.f, n2 = 0.f, n3 = 0.f;
        if (f0 < 100) {
            float4 u = *(const float4*)(none_rel + f0);
            n0 = u.x; n1 = u.y; n2 = u.z; n3 = u.w;
        }
        float ss   = half_reduce(n0*n0 + n1*n1 + n2*n2 + n3*n3);
        float inv_nr = 1.f / fmaxf(sqrtf(ss), 1e-12f);
        float dot  = half_reduce(r0*n0 + r1*n1 + r2*n2 + r3*n3) * inv_nr;
        float sq   = half_reduce(r0*r0 + r1*r1 + r2*r2 + r3*r3);
        es = __expf(-dot / fmaxf(sqrtf(sq), 1e-12f));
    }

    // ---- stores: one float4 out-store + one dword table-store per lane.
    //      Table store goes to byte offset f0 (matches the read layout). ----
    if (live) {
        *(float4*)(outp + (size_t)n * ROW_STRIDE + f0) = make_float4(r0, r1, r2, r3);
    }
    if constexpr (WRITE_TAB) {
        if (valid_n) {
            unsigned word = live ? pb4(r0, r1, r2, r3) : 0x80808080u;
            if (f0 == 112) word = __float_as_uint(es);   // weight slot (chunk7,grp0)
            *(unsigned*)(tab_out + ((size_t)n << 7) + (unsigned)f0) = word;
        }
    }
}

// ---------------------------------------------------------------------------
// Fallback attention kernel (f32 path, workspace too small for tables).
// ---------------------------------------------------------------------------
__global__ __launch_bounds__(256) void attn_f32_kernel(
    const float* __restrict__ prev,
    float* __restrict__ outp,
    const int2* __restrict__ adj2,
    const int* __restrict__ start,
    const float* __restrict__ escore_in,
    float* __restrict__ escore_out,
    const float* __restrict__ none_rel,
    int N)
{
    int waveId = (int)((blockIdx.x * blockDim.x + threadIdx.x) >> 6);
    int lane = threadIdx.x & 63;
    int h32  = lane >> 5;
    int l    = lane & 31;
    int n    = waveId * 2 + h32;
    const bool valid_n = (n < N);
    const bool fact = valid_n && (l >= 1) && (l <= 25);
    const int base = h32 << 5;

    int e0 = 0, e1 = 0;
    if (valid_n) { e0 = start[n]; e1 = start[n + 1]; }
    const int deg = e1 - e0;

    int   c0 = 0, c1 = 0;
    float w0 = 0.f, w1 = 0.f;
    if (l < deg)      { c0 = adj2[e0 + l].y;      w0 = escore_in[c0]; }
    if (l + 32 < deg) { c1 = adj2[e0 + l + 32].y; w1 = escore_in[c1]; }

    int maxdeg = deg;
    { int o = __shfl_xor(maxdeg, 32, 64); maxdeg = maxdeg > o ? maxdeg : o; }

    float d_acc = 0.f, a0 = 0.f, a1 = 0.f, a2 = 0.f, a3 = 0.f;
    const int cap1 = maxdeg < 32 ? maxdeg : 32;
    for (int r = 0; r < cap1; r += 8) {
        #pragma unroll
        for (int j = 0; j < 8; ++j) {
            int   i = r + j;
            int   c = __shfl(c0, base + i, 64);
            float w = __shfl(w0, base + i, 64);
            float p0 = 0.f, p1 = 0.f, p2 = 0.f, p3 = 0.f;
            if (fact && (i < deg)) {
                float4 v = ((const float4*)(prev + (size_t)c * ROW_STRIDE))[l - 1];
                p0 = v.x; p1 = v.y; p2 = v.z; p3 = v.w;
            }
            if (i >= deg) w = 0.f;
            d_acc += w;
            a0 += w * p0; a1 += w * p1; a2 += w * p2; a3 += w * p3;
        }
    }
    const int cap2 = maxdeg < 64 ? maxdeg : 64;
    for (int r = 32; r < cap2; r += 8) {
        #pragma unroll
        for (int j = 0; j < 8; ++j) {
            int   i = r + j;
            int   c = __shfl(c1, base + i - 32, 64);
            float w = __shfl(w1, base + i - 32, 64);
            float p0 = 0.f, p1 = 0.f, p2 = 0.f, p3 = 0.f;
            if (fact && (i < deg)) {
                float4 v = ((const float4*)(prev + (size_t)c * ROW_STRIDE))[l - 1];
                p0 = v.x; p1 = v.y; p2 = v.z; p3 = v.w;
            }
            if (i >= deg) w = 0.f;
            d_acc += w;
            a0 += w * p0; a1 += w * p1; a2 += w * p2; a3 += w * p3;
        }
    }
    for (int e = e0 + 64; e < e1; ++e) {
        int c = adj2[e].y;
        float w = escore_in[c];
        float p0 = 0.f, p1 = 0.f, p2 = 0.f, p3 = 0.f;
        if (fact) {
            float4 v = ((const float4*)(prev + (size_t)c * ROW_STRIDE))[l - 1];
            p0 = v.x; p1 = v.y; p2 = v.z; p3 = v.w;
        }
        d_acc += w;
        a0 += w * p0; a1 += w * p1; a2 += w * p2; a3 += w * p3;
    }

    const float inv_d = (deg > 0) ? 1.f / d_acc : 0.f;
    float r0 = fast_tanh(a0 * inv_d);
    float r1 = fast_tanh(a1 * inv_d);
    float r2 = fast_tanh(a2 * inv_d);
    float r3 = fast_tanh(a3 * inv_d);
    if (fact) {
        ((float4*)(outp + (size_t)n * ROW_STRIDE))[l - 1] = make_float4(r0, r1, r2, r3);
    } else {
        r0 = r1 = r2 = r3 = 0.f;
    }

    if (escore_out) {
        float nx = 0.f, ny = 0.f, nz = 0.f, nw = 0.f;
        if (l >= 1 && l <= 25) {
            float4 v = ((const float4*)none_rel)[l - 1];
            nx = v.x; ny = v.y; nz = v.z; nw = v.w;
        }
        float ss = half_reduce(nx * nx + ny * ny + nz * nz + nw * nw);
        float inv_nr = 1.f / fmaxf(sqrtf(ss), 1e-12f);
        float dot = half_reduce(r0 * nx + r1 * ny + r2 * nz + r3 * nw) * inv_nr;
        float sq  = half_reduce(r0 * r0 + r1 * r1 + r2 * r2 + r3 * r3);
        if (l == 0 && valid_n) {
            float es = __expf(-dot / fmaxf(sqrtf(sq), 1e-12f));
            escore_out[n] = es;
        }
    }
}

// ---------------------------------------------------------------------------
extern "C" void kernel_launch(void* const* d_in, const int* in_sizes, int n_in,
                              void* d_out, int out_size, void* d_ws, size_t ws_size,
                              hipStream_t stream) {
    const float* features = (const float*)d_in[0];
    // d_in[1] = rel_emb: unused by the reference
    const int*   adj      = (const int*)d_in[2];
    const float* none_rel = (const float*)d_in[3];
    float* out = (float*)d_out;

    const int N = in_sizes[0] / D_FEAT;   // 50000
    const int E = in_sizes[2] / 2;        // 800000

    // ws: start[N+1] | esc0[N] | esc1[N] | cols[E] | tab0[(N+1)*128] | tab1[(N+1)*128]
    size_t off = 0;
    auto take = [&](size_t bytes) { size_t o = off; off = (off + bytes + 127) & ~(size_t)127; return o; };
    char* w = (char*)d_ws;
    int*   start   = (int*)  (w + take(sizeof(int)   * (size_t)(N + 1)));
    float* escore0 = (float*)(w + take(sizeof(float) * (size_t)N));
    float* escore1 = (float*)(w + take(sizeof(float) * (size_t)N));
    int*   cols    = (int*)  (w + take(sizeof(int)   * (size_t)E));
    size_t tab_off0 = take((size_t)(N + 1) * ROWB);
    size_t tab_off1 = take((size_t)(N + 1) * ROWB);
    const bool use_tab = (ws_size >= off) &&
                         ((((uintptr_t)w) & 127) == 0);   // line alignment
    unsigned char* tab0 = use_tab ? (unsigned char*)(w + tab_off0) : nullptr;
    unsigned char* tab1 = use_tab ? (unsigned char*)(w + tab_off1) : nullptr;

    const int pairs = (N + 1) / 2;                       // 2 nodes per wave
    const int node_blocks = (pairs * 64 + 255) / 256;    // 1.6M threads >= E/2
    const int2* adj2 = (const int2*)adj;

    tanh_score_kernel<<<node_blocks, 256, 0, stream>>>(features, out, tab0,
                                                       escore0, none_rel,
                                                       adj, start,
                                                       use_tab ? cols : nullptr,
                                                       E, N);
    if (use_tab) {
        attn8_kernel<true><<<node_blocks, 256, 0, stream>>>(
            tab0, out + D_FEAT, tab1, cols, start, none_rel, N);
        attn8_kernel<false><<<node_blocks, 256, 0, stream>>>(
            tab1, out + 2 * D_FEAT, nullptr, cols, start, none_rel, N);
    } else {
        attn_f32_kernel<<<node_blocks, 256, 0, stream>>>(
            out, out + D_FEAT, adj2, start, escore0, escore1, none_rel, N);
        attn_f32_kernel<<<node_blocks, 256, 0, stream>>>(
            out + D_FEAT, out + 2 * D_FEAT, adj2, start, escore1, nullptr, none_rel, N);
    }
}

// Round 10
// 149.232 us; speedup vs baseline: 1.0530x; 1.0530x over previous
//
#include <hip/hip_runtime.h>
#include <hip/hip_fp16.h>
#include <math.h>

#define D_FEAT 100
#define ROW_STRIDE 300     // 3 * D_FEAT concatenated output blocks
#define ROWB 128u          // int8 table row = ONE 128-B cache line:
                           //   bytes 0..99   : biased-uint8 feats (b=rint(127x)+128)
                           //   bytes 100..111: pad 0x80 (decodes to 0)
                           //   bytes 112..115: f32 edge weight w = exp(-score)
                           //   bytes 116..127: pad 0x80
                           // row N = sentinel: w=0, feats decode to 0.
// dequant fold: x_avg = (Sum w*b)/(127*dsum) - 128/127

// ---------------------------------------------------------------------------
__device__ __forceinline__ float fast_tanh(float x) {
    float ax = fabsf(x);
    float e  = __expf(2.f * ax);
    float t  = 1.f - 2.f / (e + 1.f);
    return copysignf(t, x);
}

// biased-uint8 quantization of x in (-1,1): b = rint(127x) + 128 in [1,255]
__device__ __forceinline__ unsigned pb4(float x0, float x1, float x2, float x3) {
    unsigned b0 = (unsigned)(int)rintf(fmaf(x0, 127.f, 128.f));
    unsigned b1 = (unsigned)(int)rintf(fmaf(x1, 127.f, 128.f));
    unsigned b2 = (unsigned)(int)rintf(fmaf(x2, 127.f, 128.f));
    unsigned b3 = (unsigned)(int)rintf(fmaf(x3, 127.f, 128.f));
    return b0 | (b1 << 8) | (b2 << 16) | (b3 << 24);
}

__device__ __forceinline__ float half_reduce(float v) {
    #pragma unroll
    for (int off = 16; off; off >>= 1) v += __shfl_xor(v, off, 64);
    return v;
}

// ---------------------------------------------------------------------------
// Kernel 1: 2 nodes per wave + STREAMING CSR build + cols extraction.
//  CSR: adj rows are sorted; thread t owns edges 2t,2t+1 (the same uint4 it
//  loads for cols), writes start[j] at row boundaries. No binary search --
//  the old 20-deep dependent random-load chain is gone.
// Lane convention (shifted): lanes 1..25 hold elems 4(l-1)..4(l-1)+3.
// ---------------------------------------------------------------------------
__global__ __launch_bounds__(256) void tanh_score_kernel(
    const float* __restrict__ features,
    float* __restrict__ out,
    unsigned char* __restrict__ tab0,        // (N+1) x 128-B rows or null
    float* __restrict__ escore0,
    const float* __restrict__ none_rel,
    const int* __restrict__ adj,
    int* __restrict__ startArr,
    int* __restrict__ cols,                  // packed col indices (E)
    int E, int N)
{
    int gtid = blockIdx.x * blockDim.x + threadIdx.x;
    // cols extraction + streaming CSR boundaries (E even; grid covers E/2)
    if (gtid < (E >> 1)) {
        uint4 v = ((const uint4*)adj)[gtid];       // edges 2t,2t+1: {r0,c0,r1,c1}
        if (cols) ((int2*)cols)[gtid] = make_int2((int)v.y, (int)v.w);
        const int e  = gtid << 1;
        const int ra = (int)v.x, rb = (int)v.z;
        if (gtid == 0)
            for (int j = 0; j <= ra; ++j) startArr[j] = 0;
        for (int j = ra + 1; j <= rb; ++j) startArr[j] = e + 1;
        const int rc = (e + 2 < E) ? adj[2 * (e + 2)] : N;
        for (int j = rb + 1; j <= rc; ++j) startArr[j] = e + 2;
    }
    // sentinel row N: feats decode to 0, w = 0.0f (bytes 112..115)
    if (tab0 && gtid < 8) {
        uint4 z = make_uint4(0x80808080u, 0x80808080u, 0x80808080u, 0x80808080u);
        if (gtid == 7) z.x = 0u;                   // f32 0.0 at 112..115
        *(uint4*)(tab0 + (((size_t)N) << 7) + ((size_t)gtid << 4)) = z;
    }

    int waveId = gtid >> 6;
    int lane = threadIdx.x & 63;
    int h32  = lane >> 5;
    int l    = lane & 31;
    int n    = waveId * 2 + h32;
    const bool valid_n = (n < N);
    const bool fact = valid_n && (l >= 1) && (l <= 25);

    float x0 = 0.f, x1 = 0.f, x2 = 0.f, x3 = 0.f;
    if (fact) {
        float4 f = ((const float4*)(features + (size_t)n * D_FEAT))[l - 1];
        x0 = fast_tanh(f.x); x1 = fast_tanh(f.y);
        x2 = fast_tanh(f.z); x3 = fast_tanh(f.w);
        ((float4*)(out + (size_t)n * ROW_STRIDE))[l - 1] = make_float4(x0, x1, x2, x3);
    }
    unsigned char* row = tab0 ? (tab0 + ((size_t)n << 7)) : nullptr;
    if (row && valid_n) {
        if (l >= 1 && l <= 25) {
            *(unsigned*)(row + 4 * (l - 1)) = pb4(x0, x1, x2, x3);  // bytes 0..99
        } else if (l >= 26 && l != 29) {
            *(unsigned*)(row + 4 * (l - 1)) = 0x80808080u;          // 100..123 minus 112..115
        } else if (l == 0) {
            *(unsigned*)(row + 124) = 0x80808080u;                  // 124..127
        }
    }

    float nx = 0.f, ny = 0.f, nz = 0.f, nw = 0.f;
    if (l >= 1 && l <= 25) {
        float4 v = ((const float4*)none_rel)[l - 1];
        nx = v.x; ny = v.y; nz = v.z; nw = v.w;
    }
    float ss = half_reduce(nx * nx + ny * ny + nz * nz + nw * nw);
    float inv_nr = 1.f / fmaxf(sqrtf(ss), 1e-12f);

    float dot = half_reduce(x0 * nx + x1 * ny + x2 * nz + x3 * nw) * inv_nr;
    float sq  = half_reduce(x0 * x0 + x1 * x1 + x2 * x2 + x3 * x3);
    if (l == 0 && valid_n) {
        float es = __expf(-dot / fmaxf(sqrtf(sq), 1e-12f));
        escore0[n] = es;
        if (row) *(float*)(row + 112) = es;    // embedded weight
    }
}

// ---------------------------------------------------------------------------
// Kernel 2: fused attention, 2 nodes per wave, 128-B rows with embedded w.
//  EXACT round-8 structure (best verified). Per 32-half: grp = hl>>3 picks
//  the edge (4 per load), chunk = hl&7 the 16-B sub-block. Weight comes from
//  the gathered row (lane grp*8+7, bytes 112..115) -> no esc gather.
//  Invalid slots point at sentinel row N (w=0): no masking in the hot loop.
//  (Round-9's 8-deep load hoist REVERTED: consuming still drains vmcnt over
//  all 8 loads, no latency hidden, +1.5us/dispatch measured.)
//  Lane hl owns features f0..f0+3, f0 = 16*chunk + 4*grp (bijection to
//  {0,4,...,124}); all row stores use offset f0 to match the read layout.
// ---------------------------------------------------------------------------
template <bool WRITE_TAB>
__global__ __launch_bounds__(256) void attn8_kernel(
    const unsigned char* __restrict__ tab,   // (N+1) x 128-B rows
    float* __restrict__ outp,
    unsigned char* __restrict__ tab_out,     // next table (WRITE_TAB)
    const int* __restrict__ cols,
    const int* __restrict__ start,
    const float* __restrict__ none_rel,
    int N)
{
    if constexpr (WRITE_TAB) {               // maintain sentinel in next table
        if (blockIdx.x == 0 && threadIdx.x < 8) {
            uint4 z = make_uint4(0x80808080u, 0x80808080u, 0x80808080u, 0x80808080u);
            if (threadIdx.x == 7) z.x = 0u;
            *(uint4*)(tab_out + (((size_t)N) << 7) + ((size_t)threadIdx.x << 4)) = z;
        }
    }

    const int waveId = (int)((blockIdx.x * blockDim.x + threadIdx.x) >> 6);
    const int lane = threadIdx.x & 63;
    const int h32  = lane >> 5;
    const int hl   = lane & 31;
    const int base = h32 << 5;
    const int n    = waveId * 2 + h32;
    const bool valid_n = (n < N);

    const int grp   = hl >> 3;                 // edge slot within a load
    const int chunk = hl & 7;                  // 16-B sub-block within row
    const unsigned suboff = (unsigned)(chunk << 4);
    const int wl = base + (grp << 3) + 7;      // lane holding w of my edge

    int e0 = 0, e1 = 0;
    if (valid_n) { e0 = start[n]; e1 = start[n + 1]; }
    const int deg = e1 - e0;
    int maxdeg = deg;
    { int o = __shfl_xor(maxdeg, 32, 64); maxdeg = maxdeg > o ? maxdeg : o; }

    // stage cols for up to 64 edges; invalid slots -> sentinel row N
    int c0 = N, c1 = N;
    if (hl < deg)      c0 = cols[e0 + hl];
    if (hl + 32 < deg) c1 = cols[e0 + hl + 32];

    float a[16];
    #pragma unroll
    for (int k = 0; k < 16; ++k) a[k] = 0.f;
    float dsum = 0.f;

#define ACC16(V, W)                                                           \
    {                                                                         \
        unsigned _d;                                                          \
        _d = (V).x;                                                           \
        a[0]  = fmaf((float)(_d & 255u),         (W), a[0]);                  \
        a[1]  = fmaf((float)((_d >> 8) & 255u),  (W), a[1]);                  \
        a[2]  = fmaf((float)((_d >> 16) & 255u), (W), a[2]);                  \
        a[3]  = fmaf((float)(_d >> 24),          (W), a[3]);                  \
        _d = (V).y;                                                           \
        a[4]  = fmaf((float)(_d & 255u),         (W), a[4]);                  \
        a[5]  = fmaf((float)((_d >> 8) & 255u),  (W), a[5]);                  \
        a[6]  = fmaf((float)((_d >> 16) & 255u), (W), a[6]);                  \
        a[7]  = fmaf((float)(_d >> 24),          (W), a[7]);                  \
        _d = (V).z;                                                           \
        a[8]  = fmaf((float)(_d & 255u),         (W), a[8]);                  \
        a[9]  = fmaf((float)((_d >> 8) & 255u),  (W), a[9]);                  \
        a[10] = fmaf((float)((_d >> 16) & 255u), (W), a[10]);                 \
        a[11] = fmaf((float)(_d >> 24),          (W), a[11]);                 \
        _d = (V).w;                                                           \
        a[12] = fmaf((float)(_d & 255u),         (W), a[12]);                 \
        a[13] = fmaf((float)((_d >> 8) & 255u),  (W), a[13]);                 \
        a[14] = fmaf((float)((_d >> 16) & 255u), (W), a[14]);                 \
        a[15] = fmaf((float)(_d >> 24),          (W), a[15]);                 \
    }

    // 16 edges per half per iteration, 4 line-gathers in flight,
    // w extracted from the gathered rows (lane wl), dsum in-loop.
#define BATCH16(CST, RBASE)                                                   \
    {                                                                         \
        const int sA = base + (RBASE) + grp;                                  \
        int   cA = __shfl((CST), sA,      64), cB = __shfl((CST), sA + 4, 64);\
        int   cC = __shfl((CST), sA + 8,  64), cD = __shfl((CST), sA + 12,64);\
        const uint4 vA = *(const uint4*)(tab + (((size_t)(unsigned)cA) << 7) + suboff); \
        const uint4 vB = *(const uint4*)(tab + (((size_t)(unsigned)cB) << 7) + suboff); \
        const uint4 vC = *(const uint4*)(tab + (((size_t)(unsigned)cC) << 7) + suboff); \
        const uint4 vD = *(const uint4*)(tab + (((size_t)(unsigned)cD) << 7) + suboff); \
        const float wA = __shfl(__uint_as_float(vA.x), wl, 64);               \
        const float wB = __shfl(__uint_as_float(vB.x), wl, 64);               \
        const float wC = __shfl(__uint_as_float(vC.x), wl, 64);               \
        const float wD = __shfl(__uint_as_float(vD.x), wl, 64);               \
        dsum += wA + wB + wC + wD;                                            \
        ACC16(vA, wA) ACC16(vB, wB) ACC16(vC, wC) ACC16(vD, wD)               \
    }

    const int cap1 = maxdeg < 32 ? maxdeg : 32;
    for (int r = 0; r < cap1; r += 16) BATCH16(c0, r)
    const int cap2 = maxdeg < 64 ? maxdeg : 64;
    for (int r = 32; r < cap2; r += 16) BATCH16(c1, r - 32)
#undef BATCH16

    // deg > 64 tail (~never): one edge per pass, group 0 accumulates
    for (int e = e0 + 64; e < e1; ++e) {
        int c = cols[e];
        const uint4 v = *(const uint4*)(tab + (((size_t)(unsigned)c) << 7) + suboff);
        float wv = __shfl(__uint_as_float(v.x), base + 7, 64);
        if (grp == 0) { ACC16(v, wv) dsum += wv; }
    }
#undef ACC16

    // ---- combine the 4 edge-groups (same chunk, different grp) ----
    #pragma unroll
    for (int k = 0; k < 16; ++k) a[k] += __shfl_xor(a[k], 16, 64);
    #pragma unroll
    for (int k = 0; k < 16; ++k) a[k] += __shfl_xor(a[k], 8, 64);
    dsum += __shfl_xor(dsum, 16, 64);
    dsum += __shfl_xor(dsum, 8, 64);

    // ---- each lane finalizes its own 4 features: f0 = 16*chunk + 4*grp ----
    const float invd = (deg > 0) ? 1.f / (127.f * dsum) : 0.f;
    const float bsh  = (deg > 0) ? (-128.f / 127.f) : 0.f;
    const int f0 = (chunk << 4) + (grp << 2);
    const bool live = valid_n && (f0 < 100);   // f0 multiple of 4 -> f0+3 <= 99
    float r0 = 0.f, r1 = 0.f, r2 = 0.f, r3 = 0.f;
    if (live) {
        r0 = fast_tanh(fmaf(a[(grp << 2) + 0], invd, bsh));
        r1 = fast_tanh(fmaf(a[(grp << 2) + 1], invd, bsh));
        r2 = fast_tanh(fmaf(a[(grp << 2) + 2], invd, bsh));
        r3 = fast_tanh(fmaf(a[(grp << 2) + 3], invd, bsh));
    }

    // ---- next-layer score (WRITE_TAB): distinct features per lane, no dup
    float es = 0.f;
    if constexpr (WRITE_TAB) {
        float n0 = 0.f, n1 = 0.f, n2 = 0.f, n3 = 0.f;
        if (f0 < 100) {
            float4 u = *(const float4*)(none_rel + f0);
            n0 = u.x; n1 = u.y; n2 = u.z; n3 = u.w;
        }
        float ss   = half_reduce(n0*n0 + n1*n1 + n2*n2 + n3*n3);
        float inv_nr = 1.f / fmaxf(sqrtf(ss), 1e-12f);
        float dot  = half_reduce(r0*n0 + r1*n1 + r2*n2 + r3*n3) * inv_nr;
        float sq   = half_reduce(r0*r0 + r1*r1 + r2*r2 + r3*r3);
        es = __expf(-dot / fmaxf(sqrtf(sq), 1e-12f));
    }

    // ---- stores: one float4 out-store + one dword table-store per lane.
    //      Table store goes to byte offset f0 (matches the read layout). ----
    if (live) {
        *(float4*)(outp + (size_t)n * ROW_STRIDE + f0) = make_float4(r0, r1, r2, r3);
    }
    if constexpr (WRITE_TAB) {
        if (valid_n) {
            unsigned word = live ? pb4(r0, r1, r2, r3) : 0x80808080u;
            if (f0 == 112) word = __float_as_uint(es);   // weight slot (chunk7,grp0)
            *(unsigned*)(tab_out + ((size_t)n << 7) + (unsigned)f0) = word;
        }
    }
}

// ---------------------------------------------------------------------------
// Fallback attention kernel (f32 path, workspace too small for tables).
// ---------------------------------------------------------------------------
__global__ __launch_bounds__(256) void attn_f32_kernel(
    const float* __restrict__ prev,
    float* __restrict__ outp,
    const int2* __restrict__ adj2,
    const int* __restrict__ start,
    const float* __restrict__ escore_in,
    float* __restrict__ escore_out,
    const float* __restrict__ none_rel,
    int N)
{
    int waveId = (int)((blockIdx.x * blockDim.x + threadIdx.x) >> 6);
    int lane = threadIdx.x & 63;
    int h32  = lane >> 5;
    int l    = lane & 31;
    int n    = waveId * 2 + h32;
    const bool valid_n = (n < N);
    const bool fact = valid_n && (l >= 1) && (l <= 25);
    const int base = h32 << 5;

    int e0 = 0, e1 = 0;
    if (valid_n) { e0 = start[n]; e1 = start[n + 1]; }
    const int deg = e1 - e0;

    int   c0 = 0, c1 = 0;
    float w0 = 0.f, w1 = 0.f;
    if (l < deg)      { c0 = adj2[e0 + l].y;      w0 = escore_in[c0]; }
    if (l + 32 < deg) { c1 = adj2[e0 + l + 32].y; w1 = escore_in[c1]; }

    int maxdeg = deg;
    { int o = __shfl_xor(maxdeg, 32, 64); maxdeg = maxdeg > o ? maxdeg : o; }

    float d_acc = 0.f, a0 = 0.f, a1 = 0.f, a2 = 0.f, a3 = 0.f;
    const int cap1 = maxdeg < 32 ? maxdeg : 32;
    for (int r = 0; r < cap1; r += 8) {
        #pragma unroll
        for (int j = 0; j < 8; ++j) {
            int   i = r + j;
            int   c = __shfl(c0, base + i, 64);
            float w = __shfl(w0, base + i, 64);
            float p0 = 0.f, p1 = 0.f, p2 = 0.f, p3 = 0.f;
            if (fact && (i < deg)) {
                float4 v = ((const float4*)(prev + (size_t)c * ROW_STRIDE))[l - 1];
                p0 = v.x; p1 = v.y; p2 = v.z; p3 = v.w;
            }
            if (i >= deg) w = 0.f;
            d_acc += w;
            a0 += w * p0; a1 += w * p1; a2 += w * p2; a3 += w * p3;
        }
    }
    const int cap2 = maxdeg < 64 ? maxdeg : 64;
    for (int r = 32; r < cap2; r += 8) {
        #pragma unroll
        for (int j = 0; j < 8; ++j) {
            int   i = r + j;
            int   c = __shfl(c1, base + i - 32, 64);
            float w = __shfl(w1, base + i - 32, 64);
            float p0 = 0.f, p1 = 0.f, p2 = 0.f, p3 = 0.f;
            if (fact && (i < deg)) {
                float4 v = ((const float4*)(prev + (size_t)c * ROW_STRIDE))[l - 1];
                p0 = v.x; p1 = v.y; p2 = v.z; p3 = v.w;
            }
            if (i >= deg) w = 0.f;
            d_acc += w;
            a0 += w * p0; a1 += w * p1; a2 += w * p2; a3 += w * p3;
        }
    }
    for (int e = e0 + 64; e < e1; ++e) {
        int c = adj2[e].y;
        float w = escore_in[c];
        float p0 = 0.f, p1 = 0.f, p2 = 0.f, p3 = 0.f;
        if (fact) {
            float4 v = ((const float4*)(prev + (size_t)c * ROW_STRIDE))[l - 1];
            p0 = v.x; p1 = v.y; p2 = v.z; p3 = v.w;
        }
        d_acc += w;
        a0 += w * p0; a1 += w * p1; a2 += w * p2; a3 += w * p3;
    }

    const float inv_d = (deg > 0) ? 1.f / d_acc : 0.f;
    float r0 = fast_tanh(a0 * inv_d);
    float r1 = fast_tanh(a1 * inv_d);
    float r2 = fast_tanh(a2 * inv_d);
    float r3 = fast_tanh(a3 * inv_d);
    if (fact) {
        ((float4*)(outp + (size_t)n * ROW_STRIDE))[l - 1] = make_float4(r0, r1, r2, r3);
    } else {
        r0 = r1 = r2 = r3 = 0.f;
    }

    if (escore_out) {
        float nx = 0.f, ny = 0.f, nz = 0.f, nw = 0.f;
        if (l >= 1 && l <= 25) {
            float4 v = ((const float4*)none_rel)[l - 1];
            nx = v.x; ny = v.y; nz = v.z; nw = v.w;
        }
        float ss = half_reduce(nx * nx + ny * ny + nz * nz + nw * nw);
        float inv_nr = 1.f / fmaxf(sqrtf(ss), 1e-12f);
        float dot = half_reduce(r0 * nx + r1 * ny + r2 * nz + r3 * nw) * inv_nr;
        float sq  = half_reduce(r0 * r0 + r1 * r1 + r2 * r2 + r3 * r3);
        if (l == 0 && valid_n) {
            float es = __expf(-dot / fmaxf(sqrtf(sq), 1e-12f));
            escore_out[n] = es;
        }
    }
}

// ---------------------------------------------------------------------------
extern "C" void kernel_launch(void* const* d_in, const int* in_sizes, int n_in,
                              void* d_out, int out_size, void* d_ws, size_t ws_size,
                              hipStream_t stream) {
    const float* features = (const float*)d_in[0];
    // d_in[1] = rel_emb: unused by the reference
    const int*   adj      = (const int*)d_in[2];
    const float* none_rel = (const float*)d_in[3];
    float* out = (float*)d_out;

    const int N = in_sizes[0] / D_FEAT;   // 50000
    const int E = in_sizes[2] / 2;        // 800000

    // ws: start[N+1] | esc0[N] | esc1[N] | cols[E] | tab0[(N+1)*128] | tab1[(N+1)*128]
    size_t off = 0;
    auto take = [&](size_t bytes) { size_t o = off; off = (off + bytes + 127) & ~(size_t)127; return o; };
    char* w = (char*)d_ws;
    int*   start   = (int*)  (w + take(sizeof(int)   * (size_t)(N + 1)));
    float* escore0 = (float*)(w + take(sizeof(float) * (size_t)N));
    float* escore1 = (float*)(w + take(sizeof(float) * (size_t)N));
    int*   cols    = (int*)  (w + take(sizeof(int)   * (size_t)E));
    size_t tab_off0 = take((size_t)(N + 1) * ROWB);
    size_t tab_off1 = take((size_t)(N + 1) * ROWB);
    const bool use_tab = (ws_size >= off) &&
                         ((((uintptr_t)w) & 127) == 0);   // line alignment
    unsigned char* tab0 = use_tab ? (unsigned char*)(w + tab_off0) : nullptr;
    unsigned char* tab1 = use_tab ? (unsigned char*)(w + tab_off1) : nullptr;

    const int pairs = (N + 1) / 2;                       // 2 nodes per wave
    const int node_blocks = (pairs * 64 + 255) / 256;    // 1.6M threads >= E/2
    const int2* adj2 = (const int2*)adj;

    tanh_score_kernel<<<node_blocks, 256, 0, stream>>>(features, out, tab0,
                                                       escore0, none_rel,
                                                       adj, start,
                                                       use_tab ? cols : nullptr,
                                                       E, N);
    if (use_tab) {
        attn8_kernel<true><<<node_blocks, 256, 0, stream>>>(
            tab0, out + D_FEAT, tab1, cols, start, none_rel, N);
        attn8_kernel<false><<<node_blocks, 256, 0, stream>>>(
            tab1, out + 2 * D_FEAT, nullptr, cols, start, none_rel, N);
    } else {
        attn_f32_kernel<<<node_blocks, 256, 0, stream>>>(
            out, out + D_FEAT, adj2, start, escore0, escore1, none_rel, N);
        attn_f32_kernel<<<node_blocks, 256, 0, stream>>>(
            out + D_FEAT, out + 2 * D_FEAT, adj2, start, escore1, nullptr, none_rel, N);
    }
}